// Round 1
// 421.903 us; speedup vs baseline: 1.4479x; 1.4479x over previous
//
#include <hip/hip_runtime.h>
#include <hip/hip_bf16.h>
#include <cstdint>

// ---------------------------------------------------------------------------
// Sampled DCT2: (1) luminance + per-8x8-block 2D DCT -> [64,1,512,512]
//               (2) exact JAX threefry permutation sampling -> [64,64,250]
//
// JAX PRNG semantics: jax_threefry_partitionable = True
//   split(key, n):   keys[i] = threefry(key, (0, i))
//   random_bits(subkey, 32, (n,)): bits[j] = o0 ^ o1 of threefry(subkey,(0,j))
//   permutation = 2 rounds of {key,sub = split(key); bits = random_bits(sub);
//       x = stable_sort_by(bits, x)}
//
// R5 rewrite: no sorting at all. final[s] = sigma0(sigma1(s)) for s<250.
//   For each round we compute the EXACT stable rank of every key via a
//   4096-bucket (top-12-bit) counting pass: packed-u16 LDS histogram ->
//   prefix sum -> scatter of (key<<32|idx) -> scan own bucket run (avg len 1)
//   comparing full 64-bit packs (exact stable tie-break, == JAX stable sort).
//   Round 1 ranks < 250 build a position->slot table; round 0 ranks look it
//   up and emit. Replaces 4 radix-256 passes + 45-stage bitonic (+60
//   barriers, ballot machinery) with 2 counting passes (~12 barriers).
// ---------------------------------------------------------------------------

#define BATCH 64
#define HW 512
#define NBLK 4096
#define NSAMPLE 250
#define IMG_ELEMS (HW * HW)

#define A0 0.35355339059327373f
#define A1 0.49039264020161522f
#define A2 0.46193976625564337f
#define A3 0.41573480615127262f
#define A4 0.35355339059327379f
#define A5 0.27778511650980111f
#define A6 0.19134171618254492f
#define A7 0.09754516100806412f

__constant__ float Qc[8][8] = {
    { A0,  A0,  A0,  A0,  A0,  A0,  A0,  A0},
    { A1,  A3,  A5,  A7, -A7, -A5, -A3, -A1},
    { A2,  A6, -A6, -A2, -A2, -A6,  A6,  A2},
    { A3, -A7, -A1, -A5,  A5,  A1,  A7, -A3},
    { A4, -A4, -A4,  A4,  A4, -A4, -A4,  A4},
    { A5, -A1,  A7,  A3, -A3, -A7,  A1, -A5},
    { A6, -A2,  A2, -A6, -A6,  A2, -A2,  A6},
    { A7, -A5,  A3, -A1,  A1, -A3,  A5, -A7},
};

__constant__ int ZIGZAG[64] = {
    0, 1, 8, 16, 9, 2, 3, 10, 17, 24, 32, 25, 18, 11, 4, 5,
    12, 19, 26, 33, 40, 48, 41, 34, 27, 20, 13, 6, 7, 14, 21, 28,
    35, 42, 49, 56, 57, 50, 43, 36, 29, 22, 15, 23, 30, 37, 44, 51,
    58, 59, 52, 45, 38, 31, 39, 46, 53, 60, 61, 54, 47, 55, 62, 63
};

// ---------------- Kernel A: luminance + 8x8 DCT ----------------------------
// Streaming form: acc = Q*Y built row-by-row (one input row live at a time),
// then D = acc*Q^T stored row-by-row. No min-waves bound: (256,4) forced
// spills in R3 (dct est. 215->255us). Let the allocator pick.
__global__ __launch_bounds__(256) void dct_kernel(const float* __restrict__ x,
                                                  float* __restrict__ out) {
    int g = blockIdx.x * 256 + threadIdx.x;   // one thread per 8x8 block
    int b  = g >> 12;
    int rr = g & 4095;
    int ai = rr >> 6, bi = rr & 63;
    int row0 = ai * 8, col0 = bi * 8;
    size_t ib = (size_t)b * 3 * IMG_ELEMS;

    float acc[8][8];  // Q * Y
#pragma unroll
    for (int k = 0; k < 8; ++k) {
        size_t off = ib + (size_t)(row0 + k) * HW + col0;
        float4 r0 = *(const float4*)(x + off);
        float4 r1 = *(const float4*)(x + off + 4);
        float4 g0 = *(const float4*)(x + off + IMG_ELEMS);
        float4 g1 = *(const float4*)(x + off + IMG_ELEMS + 4);
        float4 b0 = *(const float4*)(x + off + 2 * IMG_ELEMS);
        float4 b1 = *(const float4*)(x + off + 2 * IMG_ELEMS + 4);
        float R[8] = {r0.x, r0.y, r0.z, r0.w, r1.x, r1.y, r1.z, r1.w};
        float G[8] = {g0.x, g0.y, g0.z, g0.w, g1.x, g1.y, g1.z, g1.w};
        float B[8] = {b0.x, b0.y, b0.z, b0.w, b1.x, b1.y, b1.z, b1.w};
        float y[8];
#pragma unroll
        for (int j = 0; j < 8; ++j)
            y[j] = (0.299f * (R[j] * 255.0f) + 0.587f * (G[j] * 255.0f) +
                    0.114f * (B[j] * 255.0f)) / 255.0f;
#pragma unroll
        for (int i = 0; i < 8; ++i) {
            float q = Qc[i][k];
#pragma unroll
            for (int j = 0; j < 8; ++j)
                acc[i][j] = (k == 0) ? q * y[j] : acc[i][j] + q * y[j];
        }
    }

    size_t ob = (size_t)b * IMG_ELEMS;
#pragma unroll
    for (int i = 0; i < 8; ++i) {
        float d[8];
#pragma unroll
        for (int j = 0; j < 8; ++j) {
            float s = 0.0f;
#pragma unroll
            for (int k = 0; k < 8; ++k) s += acc[i][k] * Qc[j][k];
            d[j] = s;
        }
        float4* o = (float4*)(out + ob + (size_t)(row0 + i) * HW + col0);
        o[0] = make_float4(d[0], d[1], d[2], d[3]);
        o[1] = make_float4(d[4], d[5], d[6], d[7]);
    }
}

// ---------------- Threefry-2x32 (exact JAX rounds) -------------------------
__device__ __forceinline__ uint32_t rotl32(uint32_t v, int d) {
    return (v << d) | (v >> (32 - d));
}

__device__ __forceinline__ void tf2x32(uint32_t k0, uint32_t k1,
                                       uint32_t x0, uint32_t x1,
                                       uint32_t& o0, uint32_t& o1) {
    uint32_t ks0 = k0, ks1 = k1, ks2 = k0 ^ k1 ^ 0x1BD11BDAu;
    x0 += ks0; x1 += ks1;
#define TF_R(r) { x0 += x1; x1 = rotl32(x1, r); x1 ^= x0; }
    TF_R(13) TF_R(15) TF_R(26) TF_R(6)
    x0 += ks1; x1 += ks2 + 1u;
    TF_R(17) TF_R(29) TF_R(16) TF_R(24)
    x0 += ks2; x1 += ks0 + 2u;
    TF_R(13) TF_R(15) TF_R(26) TF_R(6)
    x0 += ks0; x1 += ks1 + 3u;
    TF_R(17) TF_R(29) TF_R(16) TF_R(24)
    x0 += ks1; x1 += ks2 + 4u;
    TF_R(13) TF_R(15) TF_R(26) TF_R(6)
    x0 += ks2; x1 += ks0 + 5u;
#undef TF_R
    o0 = x0; o1 = x1;
}

// ---------------- exact stable ranks of 4096 random keys -------------------
// Counting pass over top-12-bit buckets (expected occupancy 1/bucket).
// hist32 holds 4096 u16 counters packed 2-per-word; counts/starts <= 4096 so
// packed atomicAdd carries can never cross the halfword boundary.
// rank(j) = bucket_start + #{i in bucket : (key_i, i) < (key_j, j)}  (exact,
// stable; tie-break by index via the packed u64 compare).
__device__ __forceinline__ void rank4096(
    uint32_t s0, uint32_t s1,
    uint64_t* __restrict__ pack, uint32_t* __restrict__ hist32,
    uint32_t* __restrict__ slot32, bool zero_slot,
    int tid, int w, int lane, uint32_t* __restrict__ wsum,
    uint32_t keys[8], uint32_t ranks[8]) {
    uint16_t* hist16 = (uint16_t*)hist32;

    __syncthreads();  // prior-phase readers of pack/hist are done
#pragma unroll
    for (int q = 0; q < 4; ++q) hist32[tid + q * 512] = 0u;
    if (zero_slot) {
#pragma unroll
        for (int q = 0; q < 4; ++q) slot32[tid + q * 512] = 0xFFFFFFFFu;
    }
    // key generation overlaps the zeroing stores
#pragma unroll
    for (int e = 0; e < 8; ++e) {
        uint32_t o0, o1;
        tf2x32(s0, s1, 0u, (uint32_t)(tid + e * 512), o0, o1);
        keys[e] = o0 ^ o1;
    }
    __syncthreads();

    // histogram (packed u16 counters)
#pragma unroll
    for (int e = 0; e < 8; ++e) {
        uint32_t b = keys[e] >> 20;
        atomicAdd(&hist32[b >> 1], 1u << ((b & 1) << 4));
    }
    __syncthreads();

    // exclusive prefix sum over 4096 u16 bins (thread t owns bins 8t..8t+7)
    uint4 wv = ((const uint4*)hist32)[tid];
    uint32_t c0 = wv.x & 0xFFFFu, c1 = wv.x >> 16;
    uint32_t c2 = wv.y & 0xFFFFu, c3 = wv.y >> 16;
    uint32_t c4 = wv.z & 0xFFFFu, c5 = wv.z >> 16;
    uint32_t c6 = wv.w & 0xFFFFu, c7 = wv.w >> 16;
    uint32_t ssum = c0 + c1 + c2 + c3 + c4 + c5 + c6 + c7;
    uint32_t sc = ssum;
#pragma unroll
    for (int off = 1; off < 64; off <<= 1) {
        uint32_t t = __shfl_up(sc, off);
        if (lane >= off) sc += t;
    }
    if (lane == 63) wsum[w] = sc;
    __syncthreads();
    uint32_t ex = sc - ssum;
    for (int ww = 0; ww < w; ++ww) ex += wsum[ww];
    uint32_t p0 = ex, p1 = p0 + c0, p2 = p1 + c1, p3 = p2 + c2;
    uint32_t p4 = p3 + c3, p5 = p4 + c4, p6 = p5 + c5, p7 = p6 + c6;
    uint4 ov;
    ov.x = p0 | (p1 << 16); ov.y = p2 | (p3 << 16);
    ov.z = p4 | (p5 << 16); ov.w = p6 | (p7 << 16);
    ((uint4*)hist32)[tid] = ov;   // thread-local words: no cross-thread hazard
    __syncthreads();

    // scatter packed (key, idx); bucket offset via packed atomic
#pragma unroll
    for (int e = 0; e < 8; ++e) {
        uint32_t b = keys[e] >> 20;
        uint32_t sh = (b & 1) << 4;
        uint32_t old = atomicAdd(&hist32[b >> 1], 1u << sh);
        uint32_t pos = (old >> sh) & 0xFFFFu;
        pack[pos] = ((uint64_t)keys[e] << 32) | (uint32_t)(tid + e * 512);
    }
    __syncthreads();

    // post-scatter hist16[b] = end of run b; start of run b = hist16[b-1]
#pragma unroll
    for (int e = 0; e < 8; ++e) {
        uint32_t b = keys[e] >> 20;
        uint32_t start = b ? (uint32_t)hist16[b - 1] : 0u;
        uint32_t end = (uint32_t)hist16[b];
        uint64_t self = ((uint64_t)keys[e] << 32) | (uint32_t)(tid + e * 512);
        uint32_t r = start;
        for (uint32_t p = start; p < end; ++p)
            r += (pack[p] < self) ? 1u : 0u;
        ranks[e] = r;
    }
}

// ---------------- Kernel B: permutation + gather ---------------------------
__global__ __launch_bounds__(512) void sample_kernel(const float* __restrict__ img,
                                                     float* __restrict__ out2) {
    __shared__ __align__(16) uint64_t pack[NBLK];     // 32 KB
    __shared__ __align__(16) uint32_t hist32[2048];   // 8 KB (4096 x u16)
    __shared__ __align__(16) uint32_t slot32[2048];   // 8 KB (4096 x u16)
    __shared__ uint32_t wsum[8];
    uint16_t* slot16 = (uint16_t*)slot32;

    const int tid = threadIdx.x;
    const int w = tid >> 6;
    const int lane = tid & 63;
    const int gb = blockIdx.x;  // b*64 + c

    // partitionable split(key(0), 4096)[gb], then the two fold_in/split hops
    uint32_t k0, k1, n0, n1, sA0, sA1, sB0, sB1;
    tf2x32(0u, 0u, 0u, (uint32_t)gb, k0, k1);
    tf2x32(k0, k1, 0u, 0u, n0, n1);     // key after round 0
    tf2x32(k0, k1, 0u, 1u, sA0, sA1);   // round-0 subkey
    tf2x32(n0, n1, 0u, 1u, sB0, sB1);   // round-1 subkey

    uint32_t keys[8], ranks[8];

    // ===== round 1: position -> output-slot table =====
    // rank1(j) = s means round-1 sort takes input position j to output s.
    rank4096(sB0, sB1, pack, hist32, slot32, true, tid, w, lane, wsum, keys, ranks);
#pragma unroll
    for (int e = 0; e < 8; ++e)
        if (ranks[e] < NSAMPLE) slot16[tid + e * 512] = (uint16_t)ranks[e];

    // ===== round 0: rank0(i) = position of block i after round 0 =====
    rank4096(sA0, sA1, pack, hist32, slot32, false, tid, w, lane, wsum, keys, ranks);

    // emit: block i lands at round-0 position rank0(i); if that position is
    // one of the 250 selected by round 1, write its zigzag coefficient.
    int b = gb >> 6, c = gb & 63;
    int z = ZIGZAG[c];
    int i0z = z >> 3, j0z = z & 7;
    const float* base = img + (size_t)b * IMG_ELEMS;
#pragma unroll
    for (int e = 0; e < 8; ++e) {
        uint32_t s = slot16[ranks[e]];
        if (s != 0xFFFFu) {
            int i = tid + e * 512;
            int ai = i >> 6, bi = i & 63;
            out2[(size_t)gb * NSAMPLE + s] =
                base[(size_t)(ai * 8 + i0z) * HW + (bi * 8 + j0z)];
        }
    }
}

extern "C" void kernel_launch(void* const* d_in, const int* in_sizes, int n_in,
                              void* d_out, int out_size, void* d_ws, size_t ws_size,
                              hipStream_t stream) {
    const float* x = (const float*)d_in[0];
    float* out = (float*)d_out;
    dct_kernel<<<(BATCH * NBLK) / 256, 256, 0, stream>>>(x, out);
    sample_kernel<<<BATCH * 64, 512, 0, stream>>>(out, out + (size_t)BATCH * IMG_ELEMS);
}

// Round 2
// 414.379 us; speedup vs baseline: 1.4742x; 1.0182x over previous
//
#include <hip/hip_runtime.h>
#include <hip/hip_bf16.h>
#include <cstdint>

// ---------------------------------------------------------------------------
// Sampled DCT2: (1) luminance + per-8x8-block 2D DCT -> [64,1,512,512]
//               (2) exact JAX threefry permutation sampling -> [64,64,250]
//
// JAX PRNG semantics: jax_threefry_partitionable = True
//   split(key, n):   keys[i] = threefry(key, (0, i))
//   random_bits(subkey, 32, (n,)): bits[j] = o0 ^ o1 of threefry(subkey,(0,j))
//   permutation = 2 rounds of {key,sub = split(key); bits = random_bits(sub);
//       x = stable_sort_by(bits, x)}
//
// Rank-only formulation (R5): final[s] = sigma0(sigma1(s)); compute exact
// stable ranks per round via top-12-bit counting. R6 refinements:
//   * pack is u32: within a bucket (shared top-12 bits) the stable order is
//     exactly (low20 << 12) | idx  (idx < 4096, unique) -> u32 compare is
//     bit-identical to JAX's stable sort tie-break. Halves scatter traffic.
//   * single atomic pass: histogram atomicAdd also yields intra-bucket
//     arrival order; prefix writes inclusive ends; scatter is a plain write
//     at start(b) + ord. (Atomic count per pass: 8 -> 8, scatter 8 -> 0.)
//   * LDS 49.7 KB -> 32.8 KB -> 4 blocks/CU (32 waves/CU occupancy cap).
//
// dct_kernel (R6 rewrite): old form was grid-limited to 4 waves/SIMD with
// ~48 chained loads/thread -> latency-bound. New form: 256-thread WG stages
// an 8-row x 256-col luminance strip into 8 KB LDS ([k][j][bi] layout:
// compute lanes read 32 consecutive words + 2-lane broadcast = conflict-
// free), each thread emits one row of one 8x8 block. 8192 WGs = 32 waves/
// SIMD, ~48 VGPR -> memory-bound regime.
// ---------------------------------------------------------------------------

#define BATCH 64
#define HW 512
#define NBLK 4096
#define NSAMPLE 250
#define IMG_ELEMS (HW * HW)

#define A0 0.35355339059327373f
#define A1 0.49039264020161522f
#define A2 0.46193976625564337f
#define A3 0.41573480615127262f
#define A4 0.35355339059327379f
#define A5 0.27778511650980111f
#define A6 0.19134171618254492f
#define A7 0.09754516100806412f

__constant__ float Qc[8][8] = {
    { A0,  A0,  A0,  A0,  A0,  A0,  A0,  A0},
    { A1,  A3,  A5,  A7, -A7, -A5, -A3, -A1},
    { A2,  A6, -A6, -A2, -A2, -A6,  A6,  A2},
    { A3, -A7, -A1, -A5,  A5,  A1,  A7, -A3},
    { A4, -A4, -A4,  A4,  A4, -A4, -A4,  A4},
    { A5, -A1,  A7,  A3, -A3, -A7,  A1, -A5},
    { A6, -A2,  A2, -A6, -A6,  A2, -A2,  A6},
    { A7, -A5,  A3, -A1,  A1, -A3,  A5, -A7},
};

__constant__ int ZIGZAG[64] = {
    0, 1, 8, 16, 9, 2, 3, 10, 17, 24, 32, 25, 18, 11, 4, 5,
    12, 19, 26, 33, 40, 48, 41, 34, 27, 20, 13, 6, 7, 14, 21, 28,
    35, 42, 49, 56, 57, 50, 43, 36, 29, 22, 15, 23, 30, 37, 44, 51,
    58, 59, 52, 45, 38, 31, 39, 46, 53, 60, 61, 54, 47, 55, 62, 63
};

// ---------------- Kernel A: luminance + 8x8 DCT (LDS strip) ----------------
// WG = 256 threads handles batch b, block-row ai, half h (256 cols).
// Stage: thread t loads row k=t>>5, col-group cg=t&31 (8 px x 3 ch, float4
// pairs; per-wave 1 KB contiguous per channel-row), computes luminance,
// writes ylds[k][j][bi] (j = col within block, bi = block in strip).
// Compute: thread (i=t>>5, bi=t&31) forms acc_row(i) = Q[i,:] . Y(block bi)
// then D_row = acc_row . Q^T, stores one row (2x float4, coalesced).
__global__ __launch_bounds__(256) void dct_kernel(const float* __restrict__ x,
                                                  float* __restrict__ out) {
    __shared__ float ylds[8 * 8 * 32];  // [k][j][bi] = 8 KB

    const int t = threadIdx.x;
    const int wg = blockIdx.x;          // b*128 + ai*2 + h
    const int b = wg >> 7;
    const int ai = (wg >> 1) & 63;
    const int h = wg & 1;
    const int row0 = ai * 8;
    const int colbase = h * 256;

    // ---- stage 8 x 256 luminance strip ----
    {
        const int k = t >> 5;
        const int cg = t & 31;
        size_t off = (size_t)b * 3 * IMG_ELEMS + (size_t)(row0 + k) * HW +
                     colbase + cg * 8;
        float4 r0 = *(const float4*)(x + off);
        float4 r1 = *(const float4*)(x + off + 4);
        float4 g0 = *(const float4*)(x + off + IMG_ELEMS);
        float4 g1 = *(const float4*)(x + off + IMG_ELEMS + 4);
        float4 b0 = *(const float4*)(x + off + 2 * IMG_ELEMS);
        float4 b1 = *(const float4*)(x + off + 2 * IMG_ELEMS + 4);
        float R[8] = {r0.x, r0.y, r0.z, r0.w, r1.x, r1.y, r1.z, r1.w};
        float G[8] = {g0.x, g0.y, g0.z, g0.w, g1.x, g1.y, g1.z, g1.w};
        float B[8] = {b0.x, b0.y, b0.z, b0.w, b1.x, b1.y, b1.z, b1.w};
#pragma unroll
        for (int jj = 0; jj < 8; ++jj) {
            float y = (0.299f * (R[jj] * 255.0f) + 0.587f * (G[jj] * 255.0f) +
                       0.114f * (B[jj] * 255.0f)) / 255.0f;
            ylds[k * 256 + jj * 32 + cg] = y;  // bank = cg: 2-way (free)
        }
    }
    __syncthreads();

    // ---- per-thread: one output row of one 8x8 block ----
    const int i = t >> 5;
    const int bi = t & 31;
    float qrow[8];
#pragma unroll
    for (int k = 0; k < 8; ++k) qrow[k] = Qc[i][k];

    float acc[8];
#pragma unroll
    for (int j = 0; j < 8; ++j) acc[j] = 0.0f;
#pragma unroll
    for (int k = 0; k < 8; ++k) {
#pragma unroll
        for (int j = 0; j < 8; ++j)
            acc[j] += qrow[k] * ylds[k * 256 + j * 32 + bi];  // conflict-free
    }

    float d[8];
#pragma unroll
    for (int j = 0; j < 8; ++j) {
        float s = 0.0f;
#pragma unroll
        for (int k = 0; k < 8; ++k) s += acc[k] * Qc[j][k];
        d[j] = s;
    }
    float4* o = (float4*)(out + (size_t)b * IMG_ELEMS +
                          (size_t)(row0 + i) * HW + colbase + bi * 8);
    o[0] = make_float4(d[0], d[1], d[2], d[3]);
    o[1] = make_float4(d[4], d[5], d[6], d[7]);
}

// ---------------- Threefry-2x32 (exact JAX rounds) -------------------------
__device__ __forceinline__ uint32_t rotl32(uint32_t v, int d) {
    return (v << d) | (v >> (32 - d));
}

__device__ __forceinline__ void tf2x32(uint32_t k0, uint32_t k1,
                                       uint32_t x0, uint32_t x1,
                                       uint32_t& o0, uint32_t& o1) {
    uint32_t ks0 = k0, ks1 = k1, ks2 = k0 ^ k1 ^ 0x1BD11BDAu;
    x0 += ks0; x1 += ks1;
#define TF_R(r) { x0 += x1; x1 = rotl32(x1, r); x1 ^= x0; }
    TF_R(13) TF_R(15) TF_R(26) TF_R(6)
    x0 += ks1; x1 += ks2 + 1u;
    TF_R(17) TF_R(29) TF_R(16) TF_R(24)
    x0 += ks2; x1 += ks0 + 2u;
    TF_R(13) TF_R(15) TF_R(26) TF_R(6)
    x0 += ks0; x1 += ks1 + 3u;
    TF_R(17) TF_R(29) TF_R(16) TF_R(24)
    x0 += ks1; x1 += ks2 + 4u;
    TF_R(13) TF_R(15) TF_R(26) TF_R(6)
    x0 += ks2; x1 += ks0 + 5u;
#undef TF_R
    o0 = x0; o1 = x1;
}

// ---------------- exact stable ranks of 4096 random keys -------------------
// Top-12-bit counting (avg 1 elem/bucket). hist32 = 4096 u16 packed; counts
// and positions <= 4096 so packed atomic carries never cross halfwords.
// Within bucket b, stable order == ascending (low20(key) << 12 | idx) as u32
// (idx unique, < 4096) -> exact JAX stable-sort tie-break.
__device__ __forceinline__ void rank4096(
    uint32_t s0, uint32_t s1,
    uint32_t* __restrict__ pack32, uint32_t* __restrict__ hist32,
    uint32_t* __restrict__ slot32, bool zero_slot,
    int tid, int w, int lane, uint32_t* __restrict__ wsum,
    uint32_t ranks[8]) {
    uint16_t* hist16 = (uint16_t*)hist32;

    __syncthreads();  // prior-phase readers of pack/hist are done
#pragma unroll
    for (int q = 0; q < 4; ++q) hist32[tid + q * 512] = 0u;
    if (zero_slot) {
#pragma unroll
        for (int q = 0; q < 4; ++q) slot32[tid + q * 512] = 0xFFFFFFFFu;
    }
    // key generation overlaps the zeroing stores
    uint32_t keys[8];
#pragma unroll
    for (int e = 0; e < 8; ++e) {
        uint32_t o0, o1;
        tf2x32(s0, s1, 0u, (uint32_t)(tid + e * 512), o0, o1);
        keys[e] = o0 ^ o1;
    }
    __syncthreads();

    // histogram; atomic return value = intra-bucket arrival order
    uint32_t ord[8];
#pragma unroll
    for (int e = 0; e < 8; ++e) {
        uint32_t bkt = keys[e] >> 20;
        uint32_t sh = (bkt & 1) << 4;
        uint32_t old = atomicAdd(&hist32[bkt >> 1], 1u << sh);
        ord[e] = (old >> sh) & 0xFFFFu;
    }
    __syncthreads();

    // prefix sum -> INCLUSIVE ends, in place (thread owns bins 8t..8t+7)
    uint4 wv = ((const uint4*)hist32)[tid];
    uint32_t c0 = wv.x & 0xFFFFu, c1 = wv.x >> 16;
    uint32_t c2 = wv.y & 0xFFFFu, c3 = wv.y >> 16;
    uint32_t c4 = wv.z & 0xFFFFu, c5 = wv.z >> 16;
    uint32_t c6 = wv.w & 0xFFFFu, c7 = wv.w >> 16;
    uint32_t ssum = c0 + c1 + c2 + c3 + c4 + c5 + c6 + c7;
    uint32_t sc = ssum;
#pragma unroll
    for (int off = 1; off < 64; off <<= 1) {
        uint32_t t = __shfl_up(sc, off);
        if (lane >= off) sc += t;
    }
    if (lane == 63) wsum[w] = sc;
    __syncthreads();
    uint32_t ex = sc - ssum;
    for (int ww = 0; ww < w; ++ww) ex += wsum[ww];
    uint32_t p1 = ex + c0, p2 = p1 + c1, p3 = p2 + c2, p4 = p3 + c3;
    uint32_t p5 = p4 + c4, p6 = p5 + c5, p7 = p6 + c6, p8 = p7 + c7;
    uint4 ov;
    ov.x = p1 | (p2 << 16); ov.y = p3 | (p4 << 16);
    ov.z = p5 | (p6 << 16); ov.w = p7 | (p8 << 16);
    ((uint4*)hist32)[tid] = ov;   // thread-local words: no cross-thread hazard
    __syncthreads();

    // scatter (plain write; position = bucket start + arrival order)
#pragma unroll
    for (int e = 0; e < 8; ++e) {
        uint32_t bkt = keys[e] >> 20;
        uint32_t start = bkt ? (uint32_t)hist16[bkt - 1] : 0u;
        pack32[start + ord[e]] =
            ((keys[e] & 0xFFFFFu) << 12) | (uint32_t)(tid + e * 512);
        ord[e] = start;  // reuse: run start for the rank scan
    }
    __syncthreads();

    // exact rank: start + #{smaller packs in own run}
#pragma unroll
    for (int e = 0; e < 8; ++e) {
        uint32_t bkt = keys[e] >> 20;
        uint32_t start = ord[e];
        uint32_t end = (uint32_t)hist16[bkt];
        uint32_t self = ((keys[e] & 0xFFFFFu) << 12) | (uint32_t)(tid + e * 512);
        uint32_t r = start;
        for (uint32_t p = start; p < end; ++p)
            r += (pack32[p] < self) ? 1u : 0u;
        ranks[e] = r;
    }
}

// ---------------- Kernel B: permutation + gather ---------------------------
__global__ __launch_bounds__(512) void sample_kernel(const float* __restrict__ img,
                                                     float* __restrict__ out2) {
    __shared__ __align__(16) uint32_t pack32[NBLK];   // 16 KB
    __shared__ __align__(16) uint32_t hist32[2048];   // 8 KB (4096 x u16)
    __shared__ __align__(16) uint32_t slot32[2048];   // 8 KB (4096 x u16)
    __shared__ uint32_t wsum[8];
    uint16_t* slot16 = (uint16_t*)slot32;

    const int tid = threadIdx.x;
    const int w = tid >> 6;
    const int lane = tid & 63;
    const int gb = blockIdx.x;  // b*64 + c

    // partitionable split(key(0), 4096)[gb], then the two fold_in/split hops
    uint32_t k0, k1, n0, n1, sA0, sA1, sB0, sB1;
    tf2x32(0u, 0u, 0u, (uint32_t)gb, k0, k1);
    tf2x32(k0, k1, 0u, 0u, n0, n1);     // key after round 0
    tf2x32(k0, k1, 0u, 1u, sA0, sA1);   // round-0 subkey
    tf2x32(n0, n1, 0u, 1u, sB0, sB1);   // round-1 subkey

    uint32_t ranks[8];

    // ===== round 1: position -> output-slot table =====
    // rank1(j) = s means round-1 sort takes input position j to output s.
    rank4096(sB0, sB1, pack32, hist32, slot32, true, tid, w, lane, wsum, ranks);
#pragma unroll
    for (int e = 0; e < 8; ++e)
        if (ranks[e] < NSAMPLE) slot16[tid + e * 512] = (uint16_t)ranks[e];

    // ===== round 0: rank0(i) = position of block i after round 0 =====
    rank4096(sA0, sA1, pack32, hist32, slot32, false, tid, w, lane, wsum, ranks);

    // emit: block i lands at round-0 position rank0(i); if that position is
    // one of the 250 selected by round 1, write its zigzag coefficient.
    int b = gb >> 6, c = gb & 63;
    int z = ZIGZAG[c];
    int i0z = z >> 3, j0z = z & 7;
    const float* base = img + (size_t)b * IMG_ELEMS;
#pragma unroll
    for (int e = 0; e < 8; ++e) {
        uint32_t s = slot16[ranks[e]];
        if (s != 0xFFFFu) {
            int i = tid + e * 512;
            int ai = i >> 6, bi = i & 63;
            out2[(size_t)gb * NSAMPLE + s] =
                base[(size_t)(ai * 8 + i0z) * HW + (bi * 8 + j0z)];
        }
    }
}

extern "C" void kernel_launch(void* const* d_in, const int* in_sizes, int n_in,
                              void* d_out, int out_size, void* d_ws, size_t ws_size,
                              hipStream_t stream) {
    const float* x = (const float*)d_in[0];
    float* out = (float*)d_out;
    dct_kernel<<<BATCH * 128, 256, 0, stream>>>(x, out);
    sample_kernel<<<BATCH * 64, 512, 0, stream>>>(out, out + (size_t)BATCH * IMG_ELEMS);
}